// Round 5
// baseline (234.932 us; speedup 1.0000x reference)
//
#include <hip/hip_runtime.h>
#include <hip/hip_bf16.h>

#define NVOC 65
#define NE   32
#define HD   16
#define NB   65536
#define NROWS (NB * 8)                   // 524288
#define NLOG  (NROWS * NVOC)             // 34078720

// ws layout (floats): ws[0]=loss acc; wsTab = ws+16 (64B aligned), 10074 floats:
//   G1@0(4225) TVL@4225(4225) G2@8450(520) G3@8970(520) G4@9490(64) PVL@9554(520)

static __device__ __forceinline__ float readlane_f(float v, int l) {
  return __uint_as_float(__builtin_amdgcn_readlane(__float_as_uint(v), l));
}

// ---- tables kernel: 40 blocks x 256; each block recomputes the cheap projections,
//      then each THREAD computes exactly one table entry (no serial single-CU grind) ----
__global__ __launch_bounds__(256) void bigram_tables(
    const float* __restrict__ tok, const float* __restrict__ pos,
    const float* __restrict__ Wk, const float* __restrict__ bk,
    const float* __restrict__ Wq, const float* __restrict__ bq,
    const float* __restrict__ Wv, const float* __restrict__ bv,
    const float* __restrict__ Wlm, float* __restrict__ ws)
{
  // LDS: tok@0(2080) pos@2080(256) Wq@2336(512) Wk@2848(512) Wv@3360(512)
  //      Wlm@3872(1040) TQ@4912(1040) TK@5952(1040) TV@6992(1040)
  //      PQ@8032(128) PK@8160(128) PV@8288(128)  -> 8416 floats
  __shared__ float S[8416];
  const int tid = threadIdx.x;
  if (blockIdx.x == 0 && tid == 0) ws[0] = 0.f;    // loss accumulator
  for (int o = tid; o < 2080; o += 256) S[o] = tok[o];
  S[2080 + tid] = pos[tid];                        // exactly 256
  for (int o = tid; o < 512;  o += 256) {
    S[2336 + o] = Wq[o]; S[2848 + o] = Wk[o]; S[3360 + o] = Wv[o];
  }
  for (int o = tid; o < 1040; o += 256) S[3872 + o] = Wlm[o];
  __syncthreads();

  for (int o = tid; o < 1168; o += 256) {
    if (o < 1040) {
      const int a = o >> 4, h = o & 15;
      float sq = 0.f, sk = 0.f, sv = 0.f;
      #pragma unroll
      for (int c = 0; c < NE; ++c) {
        const float e = S[a*32 + c];
        sq = fmaf(e, S[2336 + c*16 + h], sq);
        sk = fmaf(e, S[2848 + c*16 + h], sk);
        sv = fmaf(e, S[3360 + c*16 + h], sv);
      }
      S[4912 + o] = sq; S[5952 + o] = sk; S[6992 + o] = sv;
    } else {
      const int o2 = o - 1040, t = o2 >> 4, h = o2 & 15;
      float sq = bq[h], sk = bk[h], sv = bv[h];
      #pragma unroll
      for (int c = 0; c < NE; ++c) {
        const float e = S[2080 + t*32 + c];
        sq = fmaf(e, S[2336 + c*16 + h], sq);
        sk = fmaf(e, S[2848 + c*16 + h], sk);
        sv = fmaf(e, S[3360 + c*16 + h], sv);
      }
      S[8032 + o2] = sq; S[8160 + o2] = sk; S[8288 + o2] = sv;
    }
  }
  __syncthreads();

  const int o = blockIdx.x * 256 + tid;            // one output per thread
  if (o >= 10074) return;
  float* wsTab = ws + 16;
  float r = 0.f; int dst;
  if (o < 4225) {                       // G1[a][b] = 0.25 * TQ[a].TK[b]
    const int a = o / 65, b = o % 65;
    #pragma unroll
    for (int h = 0; h < HD; ++h) r = fmaf(S[4912 + a*16 + h], S[5952 + b*16 + h], r);
    r *= 0.25f; dst = o;
  } else if (o < 4745) {                // G2[a][s]
    const int o2 = o - 4225, a = o2 >> 3, s2 = o2 & 7;
    #pragma unroll
    for (int h = 0; h < HD; ++h) r = fmaf(S[4912 + a*16 + h], S[8160 + s2*16 + h], r);
    r *= 0.25f; dst = 8450 + o2;
  } else if (o < 5265) {                // G3[t][b]
    const int o2 = o - 4745, t2 = o2 / 65, b = o2 % 65;
    #pragma unroll
    for (int h = 0; h < HD; ++h) r = fmaf(S[8032 + t2*16 + h], S[5952 + b*16 + h], r);
    r *= 0.25f; dst = 8970 + o2;
  } else if (o < 5329) {                // G4[t][s]
    const int o2 = o - 5265, t2 = o2 >> 3, s2 = o2 & 7;
    #pragma unroll
    for (int h = 0; h < HD; ++h) r = fmaf(S[8032 + t2*16 + h], S[8160 + s2*16 + h], r);
    r *= 0.25f; dst = 9490 + o2;
  } else if (o < 9554) {                // TVL[a][j]
    const int o2 = o - 5329, a = o2 / 65, j = o2 % 65;
    #pragma unroll
    for (int h = 0; h < HD; ++h) r = fmaf(S[6992 + a*16 + h], S[3872 + h*65 + j], r);
    dst = 4225 + o2;
  } else {                              // PVL[s][j]
    const int o2 = o - 9554, s2 = o2 / 65, j = o2 % 65;
    #pragma unroll
    for (int h = 0; h < HD; ++h) r = fmaf(S[8288 + s2*16 + h], S[3872 + h*65 + j], r);
    dst = o;
  }
  wsTab[dst] = r;
}

// ---- main kernel: 1024 blocks x 512 threads; 1 wave handles 8 batches ----
__global__ __launch_bounds__(512, 6) void bigram_main(
    const int* __restrict__ idx, const int* __restrict__ tgt,
    const float* __restrict__ blm, const float* __restrict__ ws,
    float* __restrict__ wsacc, float* __restrict__ out)
{
  __shared__ __align__(16) float S[10074];
  __shared__ float red[8];
  const int tid = threadIdx.x;
  const float* wsTab = ws + 16;
  {
    const float4* t4 = (const float4*)wsTab;
    float4* s4 = (float4*)S;
    for (int o = tid; o < 2518; o += 512) s4[o] = t4[o];   // 10072 floats
    if (tid < 2) S[10072 + tid] = wsTab[10072 + tid];
  }
  const int lane = tid & 63;
  const int w    = tid >> 6;                 // 0..7
  const int t    = lane >> 3;
  const int s    = lane & 7;
  const float blmj  = blm[lane];
  const float blm64 = blm[64];
  const int gw = blockIdx.x * 8 + w;         // 8192 waves total
  const int iv = idx[gw*64 + lane];          // element (itb*8+p) at lane itb*8+p
  const int tv = tgt[gw*64 + lane];
  __syncthreads();

  const float g4 = S[9490 + lane];           // G4[t][s], lane == t*8+s
  float pvl[8];
  #pragma unroll
  for (int k = 0; k < 8; ++k) pvl[k] = S[9554 + k*65 + lane];   // PVL[s=k][j=lane]
  const float pvl64s = S[9554 + s*65 + 64];  // PVL[s][64] for this lane's s

  float acc_lsm = 0.f, acc_tl = 0.f;
  for (int itb = 0; itb < 8; ++itb) {
    const int base = itb * 8;
    const int av  = __shfl(iv, base + s);    // token at key position s
    const int a_t = __shfl(iv, base + t);    // token at query position t
    // scaled causal score, lane = (t,s)
    float wr = S[a_t*65 + av] + S[8450 + a_t*8 + s] + S[8970 + t*65 + av] + g4;
    float e = (t >= s) ? __expf(wr) : 0.f;   // softmax over t (per column s)
    float sm = e;
    sm += __shfl_xor(sm, 8); sm += __shfl_xor(sm, 16); sm += __shfl_xor(sm, 32);
    const float wsm = __fdividef(e, sm);     // wei[t][s] at lane t*8+s
    // col-64 logits: y = wei[t][s]*M64[s]; octet-sum over s -> row t at lane t*8+s
    const float M64s = S[4225 + av*65 + 64] + pvl64s;
    float y = wsm * M64s;
    y += __shfl_xor(y, 1); y += __shfl_xor(y, 2); y += __shfl_xor(y, 4);
    const float lg64t = blm64 + y;           // logits[row t][64], valid all lanes (t=lane>>3)
    // M[k][j=lane] = TVL[a_k][j] + PVL[k][j]
    float Ms[8];
    #pragma unroll
    for (int k = 0; k < 8; ++k) {
      const int ak = __builtin_amdgcn_readlane(iv, base + k);
      Ms[k] = S[4225 + ak*65 + lane] + pvl[k];
    }
    const int rowbase = (gw*8 + itb) * 520;
    float ee[8];
    #pragma unroll
    for (int tt = 0; tt < 8; ++tt) {
      float lg = blmj;
      #pragma unroll
      for (int k = 0; k < 8; ++k)
        lg = fmaf(readlane_f(wsm, tt*8 + k), Ms[k], lg);   // wei[tt][k]
      __builtin_nontemporal_store(lg, out + rowbase + tt*65 + lane);
      ee[tt] = __expf(lg);
      const int tg  = __builtin_amdgcn_readlane(tv, base + tt);
      const int tgc = tg < 64 ? tg : 0;
      const float l_at_tg = readlane_f(lg, tgc);
      acc_tl += (tg < 64) ? l_at_tg : readlane_f(lg64t, tt*8);  // uniform
    }
    if (s == 0)
      __builtin_nontemporal_store(lg64t, out + rowbase + t*65 + 64);  // 8 lanes
    const float x64 = __expf(lg64t);         // exp(col64) of row t = lane>>3
    // row sums: octet-reduce each ee[tt] (cols), select row u, cross-octet reduce
    #pragma unroll
    for (int tt = 0; tt < 8; ++tt) {
      ee[tt] += __shfl_xor(ee[tt], 1);
      ee[tt] += __shfl_xor(ee[tt], 2);
      ee[tt] += __shfl_xor(ee[tt], 4);
    }
    const int u = lane & 7;
    float r01 = (u & 1) ? ee[1] : ee[0];
    float r23 = (u & 1) ? ee[3] : ee[2];
    float r45 = (u & 1) ? ee[5] : ee[4];
    float r67 = (u & 1) ? ee[7] : ee[6];
    float r03 = (u & 2) ? r23 : r01;
    float r47 = (u & 2) ? r67 : r45;
    float r   = (u & 4) ? r47 : r03;
    r += __shfl_xor(r, 8); r += __shfl_xor(r, 16); r += __shfl_xor(r, 32);
    r += __shfl(x64, u * 8);                 // add exp of col 64 for row u
    acc_lsm += __logf(r);                    // row u, 8 lane-copies per row
  }
  float v = acc_lsm * 0.125f - acc_tl * 0.015625f;
  v += __shfl_xor(v, 1); v += __shfl_xor(v, 2);  v += __shfl_xor(v, 4);
  v += __shfl_xor(v, 8); v += __shfl_xor(v, 16); v += __shfl_xor(v, 32);
  if (lane == 0) red[w] = v;
  __syncthreads();
  if (tid == 0) {
    float acc = red[0] + red[1] + red[2] + red[3] + red[4] + red[5] + red[6] + red[7];
    atomicAdd(wsacc, acc);
  }
}

__global__ void bigram_fin(const float* __restrict__ ws, float* __restrict__ out) {
  if (threadIdx.x == 0) out[NLOG] = ws[0] * (1.0f / (float)NROWS);
}

extern "C" void kernel_launch(void* const* d_in, const int* in_sizes, int n_in,
                              void* d_out, int out_size, void* d_ws, size_t ws_size,
                              hipStream_t stream) {
  const int* idx = (const int*)d_in[0];
  const int* tgt = (const int*)d_in[1];
  float* ws = (float*)d_ws;
  float* out = (float*)d_out;

  bigram_tables<<<40, 256, 0, stream>>>((const float*)d_in[2], (const float*)d_in[3],
                                        (const float*)d_in[4], (const float*)d_in[5],
                                        (const float*)d_in[6], (const float*)d_in[7],
                                        (const float*)d_in[8], (const float*)d_in[9],
                                        (const float*)d_in[10], ws);
  bigram_main<<<1024, 512, 0, stream>>>(idx, tgt, (const float*)d_in[11], ws, ws, out);
  bigram_fin<<<1, 1, 0, stream>>>(ws, out);
}